// Round 13
// baseline (192.501 us; speedup 1.0000x reference)
//
#include <hip/hip_runtime.h>
#include <math.h>

// ---------------------------------------------------------------------------
// GCNEncoder: 3 stacked GCNConv layers (symmetric norm, self-loops) + ReLU.
//   R13 (on R11/12 MFMA base): ALL intermediates (hs1,out1,hs2,hs3) stored
//   as bf16 -> aggregate gather bytes halve (aggs are L2/L3-throughput-bound,
//   R12 proved not latency-bound). t2 A-operand becomes exact bf16 (8 MFMA
//   /wave instead of 12). Error budget: +~1e-3 absmax (thr 6.0e-3).
//   k_normalize merged into k_init via per-block dtype detect (10 launches).
//   Carried: bf16-split MFMA t1, XCD-partitioned hist/fill, fused W3,
//   merged scan3.
// ---------------------------------------------------------------------------

#define FULL_GRID 2048
#define PARTS 8

typedef const __attribute__((address_space(1))) void* gas_ptr;
typedef __attribute__((address_space(3))) void* las_ptr;
typedef __attribute__((ext_vector_type(8))) short bf16x8;
typedef __attribute__((ext_vector_type(8))) unsigned short u16x8;
typedef __attribute__((ext_vector_type(4))) float f32x4;

__device__ __forceinline__ void gld16(const void* g, void* l) {
  __builtin_amdgcn_global_load_lds((gas_ptr)g, (las_ptr)l, 16, 0, 0);
}

__device__ __forceinline__ unsigned short f2bf(float f) {  // RNE fp32->bf16
  unsigned int u = __float_as_uint(f);
  u += 0x7FFF + ((u >> 16) & 1);
  return (unsigned short)(u >> 16);
}
__device__ __forceinline__ float bf2f(unsigned short h) {
  return __uint_as_float(((unsigned int)h) << 16);
}

// blocks 0..127: zero counts; 128..159: prep W frags; 160..1183: normalize
// edges (per-block dtype detect on the global prefix -- no flag dependency).
__global__ __launch_bounds__(256) void k_init(int* __restrict__ p, int n4,
                                              const void* __restrict__ eraw, int E,
                                              int* __restrict__ srcn,
                                              int* __restrict__ dstn,
                                              const float* __restrict__ W1,
                                              const float* __restrict__ W2,
                                              short* __restrict__ Wh1,
                                              short* __restrict__ Wl1,
                                              short* __restrict__ Wh2,
                                              short* __restrict__ Wl2) {
  const int b = blockIdx.x;
  if (b < 128) {  // zero counts
    int i = b * blockDim.x + threadIdx.x;
    const int stride = 128 * blockDim.x;
    int4* p4 = (int4*)p;
    for (; i < n4; i += stride) p4[i] = make_int4(0, 0, 0, 0);
    return;
  }
  if (b < 160) {  // W fragment prep (32 blocks)
    const int t = (b - 128) * 256 + threadIdx.x;
    const int stride = 32 * 256;
    for (int q = t; q < 4 * 4 * 64 * 8; q += stride) {  // W1: KT=4, NT=4
      const int e = q & 7, lane = (q >> 3) & 63, nt = (q >> 9) & 3, kt = q >> 11;
      const int k = kt * 32 + (lane >> 4) * 8 + e;
      const int nn = nt * 16 + (lane & 15);
      const float f = W1[k * 64 + nn];
      const unsigned short h = f2bf(f);
      Wh1[q] = (short)h;
      Wl1[q] = (short)f2bf(f - bf2f(h));
    }
    for (int q = t; q < 2 * 2 * 64 * 8; q += stride) {  // W2: KT=2, NT=2
      const int e = q & 7, lane = (q >> 3) & 63, nt = (q >> 9) & 1, kt = q >> 10;
      const int k = kt * 32 + (lane >> 4) * 8 + e;
      const int nn = nt * 16 + (lane & 15);
      const float f = W2[k * 32 + nn];
      const unsigned short h = f2bf(f);
      Wh2[q] = (short)h;
      Wl2[q] = (short)f2bf(f - bf2f(h));
    }
    return;
  }
  // normalize with per-block dtype detect (odd 32-bit words of the prefix
  // are all zero iff edges are int64 with values < 2^31).
  __shared__ int sm[256];
  const unsigned int* words = (const unsigned int*)eraw;
  sm[threadIdx.x] = (words[threadIdx.x * 2 + 1] == 0u) ? 1 : 0;
  __syncthreads();
  for (int off = 128; off > 0; off >>= 1) {
    if (threadIdx.x < off) sm[threadIdx.x] += sm[threadIdx.x + off];
    __syncthreads();
  }
  const int is64 = sm[0] > 128;
  const int nb = b - 160;
  int i = nb * 256 + threadIdx.x;
  const int stride = 1024 * 256;
  if (is64) {
    const long long* e = (const long long*)eraw;
    for (; i < E; i += stride) {
      srcn[i] = (int)e[i];
      dstn[i] = (int)e[(long long)E + i];
    }
  } else {
    const int* e = (const int*)eraw;
    for (; i < E; i += stride) {
      srcn[i] = e[i];
      dstn[i] = e[E + i];
    }
  }
}

// XCD-partitioned histogram (partition p = blockIdx&7 -> dst range [lo,hi)).
__global__ __launch_bounds__(256) void k_hist(const int* __restrict__ dstn, int E,
                                              int N, int* __restrict__ counts) {
  const int part = blockIdx.x & (PARTS - 1);
  const int lo = (int)((long long)N * part / PARTS);
  const int hi = (int)((long long)N * (part + 1) / PARTS);
  int i = (blockIdx.x >> 3) * blockDim.x + threadIdx.x;
  const int stride = (gridDim.x >> 3) * blockDim.x;
  for (; i < E; i += stride) {
    const int d = dstn[i];
    if (d >= lo && d < hi) atomicAdd(&counts[d], 1);
  }
}

__global__ __launch_bounds__(1024) void k_scan1(const int* __restrict__ counts,
                                                int* __restrict__ scanned,
                                                int* __restrict__ partials, int n) {
  __shared__ int sm[1024];
  const int i = blockIdx.x * 1024 + threadIdx.x;
  const int v = (i < n) ? counts[i] : 0;
  sm[threadIdx.x] = v;
  __syncthreads();
  for (int off = 1; off < 1024; off <<= 1) {
    int t = sm[threadIdx.x];
    int u = (threadIdx.x >= off) ? sm[threadIdx.x - off] : 0;
    __syncthreads();
    sm[threadIdx.x] = t + u;
    __syncthreads();
  }
  const int inc = sm[threadIdx.x];
  if (i < n) scanned[i] = inc - v;  // exclusive within block
  if (threadIdx.x == 1023) partials[blockIdx.x] = inc;  // block total
}

__global__ __launch_bounds__(256) void k_scan3(const int* __restrict__ scanned,
                                               const int* __restrict__ partials,
                                               int nb,
                                               const int* __restrict__ counts,
                                               int* __restrict__ offsets,
                                               int* __restrict__ cursor,
                                               float* __restrict__ dinv, int n) {
  __shared__ int ps[1024];
  for (int t = threadIdx.x; t < nb; t += 256) ps[t] = partials[t];
  __syncthreads();
  if (threadIdx.x == 0) {
    int run = 0;
    for (int b = 0; b < nb; ++b) { const int v = ps[b]; ps[b] = run; run += v; }
  }
  __syncthreads();
  int i = blockIdx.x * blockDim.x + threadIdx.x;
  const int stride = gridDim.x * blockDim.x;
  for (; i < n; i += stride) {
    const int o = scanned[i] + ps[i >> 10];
    offsets[i] = o;
    cursor[i] = o;
    dinv[i] = rsqrtf((float)counts[i] + 1.0f);  // +1 self-loop
  }
}

// XCD-partitioned fill.
__global__ __launch_bounds__(256) void k_fill(const int* __restrict__ srcn,
                                              const int* __restrict__ dstn, int E,
                                              int N, int* __restrict__ cursor,
                                              int* __restrict__ elist) {
  const int part = blockIdx.x & (PARTS - 1);
  const int lo = (int)((long long)N * part / PARTS);
  const int hi = (int)((long long)N * (part + 1) / PARTS);
  int i = (blockIdx.x >> 3) * blockDim.x + threadIdx.x;
  const int stride = (gridDim.x >> 3) * blockDim.x;
  for (; i < E; i += stride) {
    const int d = dstn[i];
    if (d >= lo && d < hi) elist[atomicAdd(&cursor[d], 1)] = srcn[i];
  }
}

// hs1 = dinv .* (X @ W1) via 3-term bf16-split MFMA; OUTPUT IS bf16.
template <int F_IN, int F_OUT>
__global__ __launch_bounds__(256) void k_transform_mfma(
    const float* __restrict__ X, const short* __restrict__ Wh,
    const short* __restrict__ Wl, const float* __restrict__ dinv,
    unsigned short* __restrict__ H, int n) {
  constexpr int KT = F_IN / 32;
  constexpr int NT = F_OUT / 16;
  constexpr int K4f = F_IN / 4;
  constexpr int SLOTS = F_IN / 8;
  constexpr int TILE_M = 64;
  constexpr int WFRAG = KT * NT * 64 * 8;
  static_assert((WFRAG * 2) % 1024 == 0, "W segs");

  __shared__ __align__(16) unsigned short Xh[TILE_M * F_IN];
  __shared__ __align__(16) unsigned short Xl[TILE_M * F_IN];
  __shared__ __align__(16) unsigned short Whs[WFRAG];
  __shared__ __align__(16) unsigned short Wls[WFRAG];

  const int tid = threadIdx.x;
  const int lane = tid & 63;
  const int wid = tid >> 6;
  const long long base = (long long)blockIdx.x * TILE_M;

  constexpr int WSEGS = WFRAG * 2 / 1024;
  for (int seg = wid; seg < WSEGS; seg += 4) {
    gld16((const char*)Wh + seg * 1024 + lane * 16, (char*)Whs + seg * 1024);
    gld16((const char*)Wl + seg * 1024 + lane * 16, (char*)Wls + seg * 1024);
  }

  const float4* __restrict__ X4 = (const float4*)X;
  for (int g = tid; g < TILE_M * K4f; g += 256) {
    const int row = g / K4f, c4 = g % K4f;
    float4 v = make_float4(0.f, 0.f, 0.f, 0.f);
    if (base + row < n) v = X4[(base + row) * K4f + c4];
    ushort4 hv, lv;
    hv.x = f2bf(v.x); lv.x = f2bf(v.x - bf2f(hv.x));
    hv.y = f2bf(v.y); lv.y = f2bf(v.y - bf2f(hv.y));
    hv.z = f2bf(v.z); lv.z = f2bf(v.z - bf2f(hv.z));
    hv.w = f2bf(v.w); lv.w = f2bf(v.w - bf2f(hv.w));
    const int slot = (c4 >> 1) ^ (row & (SLOTS - 1));
    const int boff = row * (F_IN * 2) + slot * 16 + (c4 & 1) * 8;
    *(ushort4*)((char*)Xh + boff) = hv;
    *(ushort4*)((char*)Xl + boff) = lv;
  }
  __syncthreads();

  const int arow = lane & 15;
  const int kg = lane >> 4;
  const int lrow = wid * 16 + arow;

  f32x4 acc[NT];
  #pragma unroll
  for (int t = 0; t < NT; ++t) {
    f32x4 z = {0.f, 0.f, 0.f, 0.f};
    acc[t] = z;
  }

  #pragma unroll
  for (int kt = 0; kt < KT; ++kt) {
    const int slot = (kt * 4 + kg) ^ (lrow & (SLOTS - 1));
    const int aoff = lrow * (F_IN * 2) + slot * 16;
    const bf16x8 ah = *(const bf16x8*)((const char*)Xh + aoff);
    const bf16x8 al = *(const bf16x8*)((const char*)Xl + aoff);
    #pragma unroll
    for (int nt = 0; nt < NT; ++nt) {
      const int woff = ((kt * NT + nt) * 64 + lane) * 8;
      const bf16x8 bh = *(const bf16x8*)&Whs[woff];
      const bf16x8 bl = *(const bf16x8*)&Wls[woff];
      acc[nt] = __builtin_amdgcn_mfma_f32_16x16x32_bf16(ah, bh, acc[nt], 0, 0, 0);
      acc[nt] = __builtin_amdgcn_mfma_f32_16x16x32_bf16(ah, bl, acc[nt], 0, 0, 0);
      acc[nt] = __builtin_amdgcn_mfma_f32_16x16x32_bf16(al, bh, acc[nt], 0, 0, 0);
    }
  }

  #pragma unroll
  for (int r = 0; r < 4; ++r) {
    const long long row = base + wid * 16 + kg * 4 + r;
    if (row < n) {
      const float di = dinv[row];
      #pragma unroll
      for (int nt = 0; nt < NT; ++nt)
        H[row * F_OUT + nt * 16 + arow] = f2bf(di * acc[nt][r]);
    }
  }
}

// hs2 = dinv .* (out1 @ W2): A is EXACT bf16 (out1), only W2 split (2 MFMA).
// out1: bf16 [N,64] row-major; hs2: bf16 [N,32].
__global__ __launch_bounds__(256) void k_t2_mfma(
    const unsigned short* __restrict__ A, const short* __restrict__ Wh,
    const short* __restrict__ Wl, const float* __restrict__ dinv,
    unsigned short* __restrict__ H, int n) {
  constexpr int KT = 2, NT = 2, SLOTS = 8, TILE_M = 64;
  constexpr int WFRAG = KT * NT * 64 * 8;  // 2048 shorts

  __shared__ __align__(16) unsigned short Xs[TILE_M * 64];
  __shared__ __align__(16) unsigned short Whs[WFRAG];
  __shared__ __align__(16) unsigned short Wls[WFRAG];

  const int tid = threadIdx.x;
  const int lane = tid & 63;
  const int wid = tid >> 6;
  const long long base = (long long)blockIdx.x * TILE_M;

  for (int seg = wid; seg < WFRAG * 2 / 1024; seg += 4) {
    gld16((const char*)Wh + seg * 1024 + lane * 16, (char*)Whs + seg * 1024);
    gld16((const char*)Wl + seg * 1024 + lane * 16, (char*)Wls + seg * 1024);
  }

  if (base + TILE_M <= n) {  // full tile: async staged, pre-swizzled source
    #pragma unroll
    for (int j = 0; j < 8; ++j) {  // 8 segs of 1KB (64 slots of 16B)
      const int seg = wid * 2 + (j & 1) + (j >> 1) * 8;  // any seg cover works
      // simpler: two passes of segs per wave
      (void)seg;
    }
    // plain coverage: segs 0..7, wave w handles segs {w, w+4}
    #pragma unroll
    for (int j = 0; j < 2; ++j) {
      const int seg = wid + j * 4;
      const int slot = seg * 64 + lane;
      const int row = slot >> 3;
      const int c = slot & 7;
      gld16(&A[(base + row) * 64 + ((c ^ (row & 7)) * 8)], &Xs[seg * 512]);
    }
  } else {
    for (int slot = tid; slot < TILE_M * SLOTS; slot += 256) {
      const int row = slot >> 3;
      const int c = slot & 7;
      u16x8 v = {0, 0, 0, 0, 0, 0, 0, 0};
      if (base + row < n)
        v = *(const u16x8*)&A[(base + row) * 64 + ((c ^ (row & 7)) * 8)];
      *(u16x8*)&Xs[slot * 8] = v;
    }
  }
  __syncthreads();

  const int arow = lane & 15;
  const int kg = lane >> 4;
  const int lrow = wid * 16 + arow;

  f32x4 acc[NT];
  #pragma unroll
  for (int t = 0; t < NT; ++t) {
    f32x4 z = {0.f, 0.f, 0.f, 0.f};
    acc[t] = z;
  }

  #pragma unroll
  for (int kt = 0; kt < KT; ++kt) {
    const int slot = (kt * 4 + kg) ^ (lrow & 7);
    const bf16x8 ah = *(const bf16x8*)&Xs[lrow * 64 + slot * 8];
    #pragma unroll
    for (int nt = 0; nt < NT; ++nt) {
      const int woff = ((kt * NT + nt) * 64 + lane) * 8;
      const bf16x8 bh = *(const bf16x8*)&Whs[woff];
      const bf16x8 bl = *(const bf16x8*)&Wls[woff];
      acc[nt] = __builtin_amdgcn_mfma_f32_16x16x32_bf16(ah, bh, acc[nt], 0, 0, 0);
      acc[nt] = __builtin_amdgcn_mfma_f32_16x16x32_bf16(ah, bl, acc[nt], 0, 0, 0);
    }
  }

  #pragma unroll
  for (int r = 0; r < 4; ++r) {
    const long long row = base + wid * 16 + kg * 4 + r;
    if (row < n) {
      const float di = dinv[row];
      #pragma unroll
      for (int nt = 0; nt < NT; ++nt)
        H[row * 32 + nt * 16 + arow] = f2bf(di * acc[nt][r]);
    }
  }
}

// bf16 edge-group-parallel aggregate. Wave = one dst node; LPE=F/8 lanes/edge
// (16B bf16x8 slice), EPW=64/LPE edges per instr, 2 batches in flight.
// out1 = relu(b + dinv*(self + sum)) stored bf16 (agg1), or
// FUSE_W3: hs3 = dinv .* (relu(out2) @ W3) packed 2xbf16 in a uint (agg2).
template <int F, bool FUSE_W3>
__global__ __launch_bounds__(256) void k_agg_bf(const unsigned short* __restrict__ HS,
                                                const float* __restrict__ dinv,
                                                const int* __restrict__ offsets,
                                                const int* __restrict__ counts,
                                                const int* __restrict__ elist,
                                                const float* __restrict__ bias,
                                                const float* __restrict__ W3,
                                                void* __restrict__ outv, int n) {
  constexpr int LPE = F / 8;        // lanes per edge
  constexpr int EPW = 64 / LPE;     // edges per wave-instruction
  const int lane = threadIdx.x & 63;
  const int wv = (blockIdx.x * (blockDim.x >> 6)) + (threadIdx.x >> 6);
  const int nwaves = gridDim.x * (blockDim.x >> 6);
  const int g = lane / LPE;
  const int fl = lane % LPE;

  float bf[8];
  #pragma unroll
  for (int j = 0; j < 8; ++j) bf[j] = bias[fl * 8 + j];
  float w3a[8], w3b[8];
  if (FUSE_W3) {
    #pragma unroll
    for (int j = 0; j < 8; ++j) {
      w3a[j] = W3[(fl * 8 + j) * 2 + 0];
      w3b[j] = W3[(fl * 8 + j) * 2 + 1];
    }
  }

  for (long long d = wv; d < n; d += nwaves) {
    const float di = dinv[d];
    const int start = offsets[d];
    const int cnt = counts[d];
    float a[8] = {0.f, 0.f, 0.f, 0.f, 0.f, 0.f, 0.f, 0.f};
    if (g == 0) {
      const u16x8 v = *(const u16x8*)&HS[d * F + fl * 8];
      #pragma unroll
      for (int j = 0; j < 8; ++j) a[j] = bf2f(v[j]);
    }
    const int cl = cnt > 0 ? cnt - 1 : 0;
    for (int j0 = 0; j0 < cnt; j0 += 2 * EPW) {
      const int e0 = j0 + g;
      const int e1 = j0 + EPW + g;
      const int i0 = elist[start + (e0 < cnt ? e0 : cl)];
      const int i1 = elist[start + (e1 < cnt ? e1 : cl)];
      const u16x8 v0 = *(const u16x8*)&HS[(long long)i0 * F + fl * 8];
      const u16x8 v1 = *(const u16x8*)&HS[(long long)i1 * F + fl * 8];
      if (e0 < cnt) {
        #pragma unroll
        for (int j = 0; j < 8; ++j) a[j] += bf2f(v0[j]);
      }
      if (e1 < cnt) {
        #pragma unroll
        for (int j = 0; j < 8; ++j) a[j] += bf2f(v1[j]);
      }
    }
    #pragma unroll
    for (int m = LPE; m < 64; m <<= 1) {
      #pragma unroll
      for (int j = 0; j < 8; ++j) a[j] += __shfl_xor(a[j], m, 64);
    }
    float r[8];
    #pragma unroll
    for (int j = 0; j < 8; ++j) r[j] = fmaxf(fmaf(di, a[j], bf[j]), 0.f);
    if (!FUSE_W3) {
      if (g == 0) {
        u16x8 pv;
        #pragma unroll
        for (int j = 0; j < 8; ++j) pv[j] = f2bf(r[j]);
        *(u16x8*)&((unsigned short*)outv)[d * F + fl * 8] = pv;
      }
    } else {
      float t0 = 0.f, t1 = 0.f;
      #pragma unroll
      for (int j = 0; j < 8; ++j) {
        t0 = fmaf(r[j], w3a[j], t0);
        t1 = fmaf(r[j], w3b[j], t1);
      }
      #pragma unroll
      for (int m = 1; m < LPE; m <<= 1) {
        t0 += __shfl_xor(t0, m, 64);
        t1 += __shfl_xor(t1, m, 64);
      }
      if (lane == 0) {
        const unsigned int pk = (unsigned int)f2bf(di * t0) |
                                ((unsigned int)f2bf(di * t1) << 16);
        ((unsigned int*)outv)[d] = pk;
      }
    }
  }
}

// layer-3 aggregate: hs3 packed 2xbf16/node; out = relu(b3 + di*(self+sum)).
__global__ __launch_bounds__(256) void k_agg3(const unsigned int* __restrict__ HS,
                                              const float* __restrict__ dinv,
                                              const int* __restrict__ offsets,
                                              const int* __restrict__ counts,
                                              const int* __restrict__ elist,
                                              const float* __restrict__ b3,
                                              float* __restrict__ out, int n) {
  const float b30 = b3[0], b31 = b3[1];
  int d = blockIdx.x * blockDim.x + threadIdx.x;
  const int stride = gridDim.x * blockDim.x;
  for (; d < n; d += stride) {
    const float di = dinv[d];
    const unsigned int self = HS[d];
    float a0 = bf2f((unsigned short)(self & 0xFFFF));
    float a1 = bf2f((unsigned short)(self >> 16));
    const int start = offsets[d];
    const int cnt = counts[d];
    for (int j = 0; j < cnt; j += 8) {
      unsigned int u[8];
      #pragma unroll
      for (int t = 0; t < 8; ++t) {
        const int jj = (j + t < cnt) ? (j + t) : j;
        u[t] = HS[elist[start + jj]];
      }
      #pragma unroll
      for (int t = 0; t < 8; ++t) {
        if (j + t < cnt) {
          a0 += bf2f((unsigned short)(u[t] & 0xFFFF));
          a1 += bf2f((unsigned short)(u[t] >> 16));
        }
      }
    }
    out[d * 2 + 0] = fmaxf(fmaf(di, a0, b30), 0.f);
    out[d * 2 + 1] = fmaxf(fmaf(di, a1, b31), 0.f);
  }
}

extern "C" void kernel_launch(void* const* d_in, const int* in_sizes, int n_in,
                              void* d_out, int out_size, void* d_ws, size_t ws_size,
                              hipStream_t stream) {
  const float* x = (const float*)d_in[0];
  const void* eraw = d_in[1];
  const float* W1 = (const float*)d_in[2];
  const float* b1 = (const float*)d_in[3];
  const float* W2 = (const float*)d_in[4];
  const float* b2 = (const float*)d_in[5];
  const float* W3 = (const float*)d_in[6];
  const float* b3 = (const float*)d_in[7];
  float* out = (float*)d_out;

  const int N = in_sizes[0] / 128;  // 100000
  const int E = in_sizes[1] / 2;    // 600000

  char* ws = (char*)d_ws;
  size_t off = 0;
  auto alloc = [&](size_t bytes) -> char* {
    char* p = ws + off;
    off = (off + bytes + 255) & ~(size_t)255;
    return p;
  };
  int*            counts   = (int*)alloc((size_t)N * 4 + 16);
  int*            scanned  = (int*)alloc((size_t)N * 4);
  int*            partials = (int*)alloc(1024 * 4);
  int*            offsets  = (int*)alloc((size_t)N * 4);
  int*            cursor   = (int*)alloc((size_t)N * 4);
  int*            srcn     = (int*)alloc((size_t)E * 4);
  int*            dstn     = (int*)alloc((size_t)E * 4);
  int*            elist    = (int*)alloc((size_t)E * 4);
  float*          dinv     = (float*)alloc((size_t)N * 4);
  short*          Wh1      = (short*)alloc(4 * 4 * 64 * 8 * 2);
  short*          Wl1      = (short*)alloc(4 * 4 * 64 * 8 * 2);
  short*          Wh2      = (short*)alloc(2 * 2 * 64 * 8 * 2);
  short*          Wl2      = (short*)alloc(2 * 2 * 64 * 8 * 2);
  unsigned short* hbuf     = (unsigned short*)alloc((size_t)N * 64 * 2);  // hs1 bf16; later hs3 uint
  unsigned short* obuf     = (unsigned short*)alloc((size_t)N * 64 * 2);  // out1 bf16
  unsigned short* h2buf    = (unsigned short*)alloc((size_t)N * 32 * 2);  // hs2 bf16
  (void)ws_size; (void)n_in; (void)out_size;

  // ---- CSR build + W pre-pack (zero+prepw+normalize fused) ----
  k_init<<<1184, 256, 0, stream>>>(counts, (N + 3) / 4, eraw, E, srcn, dstn,
                                   W1, W2, Wh1, Wl1, Wh2, Wl2);
  k_hist<<<FULL_GRID, 256, 0, stream>>>(dstn, E, N, counts);
  const int NB = (N + 1023) >> 10;
  k_scan1<<<NB, 1024, 0, stream>>>(counts, scanned, partials, N);
  k_scan3<<<(N + 255) / 256, 256, 0, stream>>>(scanned, partials, NB, counts,
                                               offsets, cursor, dinv, N);
  k_fill<<<FULL_GRID, 256, 0, stream>>>(srcn, dstn, E, N, cursor, elist);

  // ---- layer 1: hs1(bf16) = dinv.*(x@W1); out1(bf16) = relu(agg(hs1)) ----
  k_transform_mfma<128, 64><<<(N + 63) / 64, 256, 0, stream>>>(
      x, Wh1, Wl1, dinv, hbuf, N);
  k_agg_bf<64, false><<<FULL_GRID, 256, 0, stream>>>(
      hbuf, dinv, offsets, counts, elist, b1, nullptr, obuf, N);

  // ---- layer 2: hs2(bf16) = dinv.*(out1@W2); agg+ReLU+W3 -> hs3(2xbf16) ----
  k_t2_mfma<<<(N + 63) / 64, 256, 0, stream>>>(obuf, Wh2, Wl2, dinv, h2buf, N);
  k_agg_bf<32, true><<<FULL_GRID, 256, 0, stream>>>(
      h2buf, dinv, offsets, counts, elist, b2, W3, hbuf, N);

  // ---- layer 3: agg hs3 + ReLU -> out (fp32) ----
  k_agg3<<<(N + 255) / 256, 256, 0, stream>>>((const unsigned int*)hbuf, dinv,
                                              offsets, counts, elist, b3, out, N);
}